// Round 1
// baseline (17.468 us; speedup 1.0000x reference)
//
#include <hip/hip_runtime.h>
#include <math.h>

#define NI 6
#define NC 10
#define C_IN 512
#define N_POS 4096
#define B_SZ 2
#define N_TOT (B_SZ * N_POS)   // 8192 positions total

// ---------------------------------------------------------------------------
// K1: context = relu(Wc @ features + bc), and (if beta != 0) Q,K,V,QD,KD.
// Grid: N_TOT/32 = 256 blocks of 256 threads.
// Each block: 32 positions x 8 chunks of 64 channels.
// Thread t: pos = t&31, chunk = t>>5. Coalesced: for fixed c, lanes 0..31 read
// 32 consecutive floats (128B) and lanes 32..63 another 128B segment.
// ---------------------------------------------------------------------------
__global__ __launch_bounds__(256) void k_front(
    const float* __restrict__ feat, const float* __restrict__ cam,
    const float* __restrict__ Wc,  const float* __restrict__ bc,
    const float* __restrict__ Wq,  const float* __restrict__ bq,
    const float* __restrict__ Wk,  const float* __restrict__ bk,
    const float* __restrict__ Wv,  const float* __restrict__ bv,
    const float* __restrict__ Wcq, const float* __restrict__ bcq,
    const float* __restrict__ Wck, const float* __restrict__ bck,
    const float* __restrict__ beta,
    float* __restrict__ ctx, float* __restrict__ qbuf, float* __restrict__ kbuf,
    float* __restrict__ vbuf, float* __restrict__ qdbuf, float* __restrict__ kdbuf)
{
    __shared__ float sWc[C_IN * NI];      // [c][d] layout (transposed from input)
    __shared__ float sPart[8][32][NI];    // per-chunk partial sums

    const int t = threadIdx.x;

    // Load Wc (given [NI][C_IN]) transposed into LDS as [c][d].
    for (int i = t; i < C_IN * NI; i += 256) {
        int c = i / NI, d = i - c * NI;
        sWc[i] = Wc[d * C_IN + c];
    }
    __syncthreads();

    const int pos   = t & 31;
    const int chunk = t >> 5;            // 0..7, 64 channels each
    const int p = blockIdx.x * 32 + pos; // global position (b*4096+n)
    const int b = p >> 12;
    const int n = p & 4095;

    const float* f = feat + ((size_t)b * C_IN) * N_POS + n;
    const int c0 = chunk * 64;

    float acc[NI] = {0.f, 0.f, 0.f, 0.f, 0.f, 0.f};
    #pragma unroll 8
    for (int cc = 0; cc < 64; ++cc) {
        const int c = c0 + cc;
        const float x = f[(size_t)c * N_POS];
        #pragma unroll
        for (int d = 0; d < NI; ++d) acc[d] += sWc[c * NI + d] * x;
    }
    #pragma unroll
    for (int d = 0; d < NI; ++d) sPart[chunk][pos][d] = acc[d];
    __syncthreads();

    if (t < 32) {
        const int pp = blockIdx.x * 32 + t;
        const int bb = pp >> 12;
        const int nn = pp & 4095;
        float o[NI];
        #pragma unroll
        for (int d = 0; d < NI; ++d) {
            float s = bc[d];
            #pragma unroll
            for (int ch = 0; ch < 8; ++ch) s += sPart[ch][t][d];
            o[d] = fmaxf(s, 0.f);     // relu
        }
        float* cw = ctx + (size_t)pp * NI;
        #pragma unroll
        for (int d = 0; d < NI; ++d) cw[d] = o[d];

        if (*beta != 0.f) {
            // Q, K, V = 6x6 matvecs on context
            float qv[NI], kv[NI], vv[NI];
            #pragma unroll
            for (int oo = 0; oo < NI; ++oo) {
                float s1 = bq[oo], s2 = bk[oo], s3 = bv[oo];
                #pragma unroll
                for (int d = 0; d < NI; ++d) {
                    s1 += Wq[oo * NI + d] * o[d];
                    s2 += Wk[oo * NI + d] * o[d];
                    s3 += Wv[oo * NI + d] * o[d];
                }
                qv[oo] = s1; kv[oo] = s2; vv[oo] = s3;
            }
            // QD, KD from cam
            float cv[NI];
            #pragma unroll
            for (int d = 0; d < NI; ++d)
                cv[d] = cam[((size_t)(bb * NI + d)) * N_POS + nn];
            float qdv[NI], kdv[NI];
            #pragma unroll
            for (int oo = 0; oo < NI; ++oo) {
                float s1 = bcq[oo], s2 = bck[oo];
                #pragma unroll
                for (int d = 0; d < NI; ++d) {
                    s1 += Wcq[oo * NI + d] * cv[d];
                    s2 += Wck[oo * NI + d] * cv[d];
                }
                qdv[oo] = s1; kdv[oo] = s2;
            }
            float* qw  = qbuf  + (size_t)pp * NI;
            float* kw  = kbuf  + (size_t)pp * NI;
            float* vw  = vbuf  + (size_t)pp * NI;
            float* qdw = qdbuf + (size_t)pp * NI;
            float* kdw = kdbuf + (size_t)pp * NI;
            #pragma unroll
            for (int d = 0; d < NI; ++d) {
                qw[d] = qv[d]; kw[d] = kv[d]; vw[d] = vv[d];
                qdw[d] = qdv[d]; kdw[d] = kdv[d];
            }
        }
    }
}

// ---------------------------------------------------------------------------
// K2: flash-style attention row, only when beta != 0.
// attention = softmax((QD.KD) * (Q.K) / sqrt(6)); enh = attention @ V.
// Grid: 2048 blocks x 256 thr = 4 rows/block, 64 lanes per row.
// Each lane handles 64 m's (interleaved m = mi*64+lane for coalescing),
// online softmax, then shfl_xor butterfly merge across the 64 lanes.
// ---------------------------------------------------------------------------
__global__ __launch_bounds__(256) void k_attn(
    const float* __restrict__ beta,
    const float* __restrict__ q,  const float* __restrict__ k,
    const float* __restrict__ v,  const float* __restrict__ qd,
    const float* __restrict__ kd, float* __restrict__ enh)
{
    if (*beta == 0.f) return;   // wave-uniform early exit: beta==0 => enhancement unused

    const float inv_scale = 0.40824829046386296f; // 1/sqrt(6)
    const int t    = threadIdx.x;
    const int lane = t & 63;
    const int p    = blockIdx.x * 4 + (t >> 6);   // global row 0..8191
    const int b    = p >> 12;
    const int base = b << 12;

    float qr[NI], qdr[NI];
    {
        const float* qp  = q  + (size_t)p * NI;
        const float* qdp = qd + (size_t)p * NI;
        #pragma unroll
        for (int d = 0; d < NI; ++d) { qr[d] = qp[d]; qdr[d] = qdp[d]; }
    }

    float mmax = -INFINITY, l = 0.f;
    float acc[NI] = {0.f, 0.f, 0.f, 0.f, 0.f, 0.f};

    for (int mi = 0; mi < 64; ++mi) {
        const int m = mi * 64 + lane;
        const float* kp  = k  + (size_t)(base + m) * NI;
        const float* kdp = kd + (size_t)(base + m) * NI;
        const float* vp  = v  + (size_t)(base + m) * NI;
        float s1 = 0.f, s2 = 0.f;
        #pragma unroll
        for (int d = 0; d < NI; ++d) { s1 += qr[d] * kp[d]; s2 += qdr[d] * kdp[d]; }
        const float s = s1 * s2 * inv_scale;
        const float nm = fmaxf(mmax, s);
        const float corr = __expf(mmax - nm);   // exp(-inf)=0 on first iter
        const float e = __expf(s - nm);
        l = l * corr + e;
        #pragma unroll
        for (int d = 0; d < NI; ++d) acc[d] = acc[d] * corr + e * vp[d];
        mmax = nm;
    }

    // butterfly merge of (mmax, l, acc[6]) across 64 lanes
    #pragma unroll
    for (int off = 1; off < 64; off <<= 1) {
        const float om = __shfl_xor(mmax, off);
        const float ol = __shfl_xor(l, off);
        const float nm = fmaxf(mmax, om);
        const float c1 = __expf(mmax - nm);
        const float c2 = __expf(om - nm);
        l = l * c1 + ol * c2;
        #pragma unroll
        for (int d = 0; d < NI; ++d)
            acc[d] = acc[d] * c1 + __shfl_xor(acc[d], off) * c2;
        mmax = nm;
    }

    if (lane == 0) {
        const float invl = 1.f / l;
        float* ew = enh + (size_t)p * NI;
        #pragma unroll
        for (int d = 0; d < NI; ++d) ew[d] = acc[d] * invl;
    }
}

// ---------------------------------------------------------------------------
// K3: enhanced = ctx + beta*enh; output_maps = Wo @ enhanced + bo (written to
// d_out), plus per-block partial sums for the logits mean.
// Grid: 32 blocks x 256 thr, one position per thread. Blocks 0..15 = batch 0.
// ---------------------------------------------------------------------------
__global__ __launch_bounds__(256) void k_out(
    const float* __restrict__ beta,
    const float* __restrict__ ctx, const float* __restrict__ enh,
    const float* __restrict__ Wo,  const float* __restrict__ bo,
    float* __restrict__ out, float* __restrict__ partial)
{
    __shared__ float sRed[4][NC];

    const int t = threadIdx.x;
    const int p = blockIdx.x * 256 + t;
    const int b = p >> 12;
    const int n = p & 4095;

    const float bt = *beta;
    float e[NI];
    const float* cp = ctx + (size_t)p * NI;
    if (bt != 0.f) {
        const float* ep = enh + (size_t)p * NI;
        #pragma unroll
        for (int d = 0; d < NI; ++d) e[d] = cp[d] + bt * ep[d];
    } else {
        #pragma unroll
        for (int d = 0; d < NI; ++d) e[d] = cp[d];
    }

    float sums[NC];
    #pragma unroll
    for (int o = 0; o < NC; ++o) {
        float s = 0.f;
        #pragma unroll
        for (int d = 0; d < NI; ++d) s += Wo[o * NI + d] * e[d];
        out[((size_t)(b * NC + o)) * N_POS + n] = s + bo[o];
        sums[o] = s;
    }

    // block-reduce the 10 partial sums (bo folded in at the finalize kernel)
    const int lane = t & 63, wid = t >> 6;
    #pragma unroll
    for (int o = 0; o < NC; ++o) {
        float s = sums[o];
        #pragma unroll
        for (int off = 32; off > 0; off >>= 1) s += __shfl_down(s, off);
        if (lane == 0) sRed[wid][o] = s;
    }
    __syncthreads();
    if (t < NC) {
        const float s = sRed[0][t] + sRed[1][t] + sRed[2][t] + sRed[3][t];
        partial[blockIdx.x * NC + t] = s;
    }
}

// ---------------------------------------------------------------------------
// K4: logits[b][o] = mean_n output_maps = (sum of 16 block partials)/4096 + bo
// ---------------------------------------------------------------------------
__global__ void k_logits(const float* __restrict__ partial,
                         const float* __restrict__ bo,
                         float* __restrict__ outL)
{
    const int t = threadIdx.x;
    if (t < B_SZ * NC) {
        const int b = t / NC, o = t - b * NC;
        float s = 0.f;
        #pragma unroll
        for (int blk = 0; blk < 16; ++blk) s += partial[(b * 16 + blk) * NC + o];
        outL[t] = s * (1.f / 4096.f) + bo[o];
    }
}

extern "C" void kernel_launch(void* const* d_in, const int* in_sizes, int n_in,
                              void* d_out, int out_size, void* d_ws, size_t ws_size,
                              hipStream_t stream)
{
    const float* feat = (const float*)d_in[0];
    const float* cam  = (const float*)d_in[1];
    const float* Wc  = (const float*)d_in[2];  const float* bc  = (const float*)d_in[3];
    const float* Wq  = (const float*)d_in[4];  const float* bq  = (const float*)d_in[5];
    const float* Wk  = (const float*)d_in[6];  const float* bk  = (const float*)d_in[7];
    const float* Wv  = (const float*)d_in[8];  const float* bv  = (const float*)d_in[9];
    const float* Wcq = (const float*)d_in[10]; const float* bcq = (const float*)d_in[11];
    const float* Wck = (const float*)d_in[12]; const float* bck = (const float*)d_in[13];
    const float* Wo  = (const float*)d_in[14]; const float* bo  = (const float*)d_in[15];
    const float* beta = (const float*)d_in[16];

    float* ws = (float*)d_ws;
    float* ctx     = ws;                 // [8192][6]
    float* qbuf    = ws + 49152;
    float* kbuf    = ws + 98304;
    float* vbuf    = ws + 147456;
    float* qdbuf   = ws + 196608;
    float* kdbuf   = ws + 245760;
    float* enh     = ws + 294912;
    float* partial = ws + 344064;        // [32][10]

    float* out = (float*)d_out;          // [2][10][4096] then [2][10] logits

    k_front<<<N_TOT / 32, 256, 0, stream>>>(feat, cam, Wc, bc, Wq, bq, Wk, bk,
                                            Wv, bv, Wcq, bcq, Wck, bck, beta,
                                            ctx, qbuf, kbuf, vbuf, qdbuf, kdbuf);
    k_attn<<<N_TOT / 4, 256, 0, stream>>>(beta, qbuf, kbuf, vbuf, qdbuf, kdbuf, enh);
    k_out<<<N_TOT / 256, 256, 0, stream>>>(beta, ctx, enh, Wo, bo, out, partial);
    k_logits<<<1, 64, 0, stream>>>(partial, bo, out + B_SZ * NC * N_POS);
}